// Round 3
// baseline (996.106 us; speedup 1.0000x reference)
//
#include <hip/hip_runtime.h>
#include <hip/hip_bf16.h>

#define N_NODES   20000
#define N_EDGES   100000
#define N_REL     1000
#define F_DIM     128
#define N_HEAD    4
#define HC        512      // N_HEAD * F_DIM
#define N_LAYERS  4
#define REL_EXT_ROWS 1008  // 1000 relations + 1 mean row, padded to mult of 16
#define NEG_SLOPE 0.2f

typedef __attribute__((ext_vector_type(8))) short short8;
typedef __attribute__((ext_vector_type(4))) float floatx4;

// Read input element i as float, regardless of whether inputs are fp32 or bf16.
__device__ __forceinline__ float loadIn(const void* p, size_t i, int f32) {
    if (f32) return ((const float*)p)[i];
    union { unsigned int u; float f; } c;
    c.u = ((unsigned int)((const unsigned short*)p)[i]) << 16;
    return c.f;
}

__device__ __forceinline__ unsigned short f2bf(float v) {
    __hip_bfloat16 b = __float2bfloat16(v);
    return *(unsigned short*)&b;
}

// ---------------- dtype detection ----------------
// True-bf16 N(0,1) data: no element with exponent >= 2^16. fp32 read as u16:
// every other u16 is raw mantissa bits -> ~44% have huge/NaN exponents.
__global__ void detect_kernel(const unsigned short* __restrict__ x, int* __restrict__ flag) {
    int t = threadIdx.x;  // 64
    int cnt = 0;
    for (int j = t; j < 256; j += 64) {
        int e = (x[j] >> 7) & 0xFF;
        if (e >= 143) cnt++;   // |v| >= 2^16 or NaN/Inf
    }
    for (int off = 32; off; off >>= 1) cnt += __shfl_xor(cnt, off);
    if (t == 0) flag[0] = (cnt >= 8) ? 1 : 0;
}

// ---------------- preprocessing ----------------

__global__ void hist_kernel(const int* __restrict__ dst, const int* __restrict__ rel,
                            int* __restrict__ deg, int* __restrict__ rcount) {
    int e = blockIdx.x * 256 + threadIdx.x;
    if (e < N_EDGES) {
        atomicAdd(&deg[dst[e]], 1);
        atomicAdd(&rcount[rel[e]], 1);
    }
}

__global__ void ea_mean_kernel(const int* __restrict__ rcount,
                               const void* __restrict__ relations,
                               float* __restrict__ ea_mean, const int* __restrict__ flag) {
    int c = threadIdx.x;  // 128 threads
    int f32 = flag[0];
    float acc = 0.f;
    for (int r = 0; r < N_REL; ++r)
        acc += (float)rcount[r] * loadIn(relations, (size_t)r * F_DIM + c, f32);
    ea_mean[c] = acc * (1.f / (float)N_EDGES);
}

__global__ void relext_kernel(const void* __restrict__ relations,
                              const float* __restrict__ ea_mean,
                              unsigned short* __restrict__ rel_ext, const int* __restrict__ flag) {
    int idx = blockIdx.x * 256 + threadIdx.x;
    if (idx >= REL_EXT_ROWS * F_DIM) return;
    int f32 = flag[0];
    int r = idx >> 7;
    int c = idx & 127;
    float v;
    if (r < N_REL)       v = loadIn(relations, idx, f32);
    else if (r == N_REL) v = ea_mean[c];
    else                 v = 0.f;
    rel_ext[idx] = f2bf(v);
}

__global__ void scan_kernel(const int* __restrict__ deg,
                            int* __restrict__ row_start, int* __restrict__ cursor) {
    __shared__ int part[1024];
    int t = threadIdx.x;
    const int CH = (N_NODES + 1023) / 1024;  // 20
    int base = t * CH;
    int sum = 0;
    for (int j = 0; j < CH; ++j) {
        int idx = base + j;
        if (idx < N_NODES) sum += deg[idx];
    }
    part[t] = sum;
    __syncthreads();
    for (int off = 1; off < 1024; off <<= 1) {
        int u = (t >= off) ? part[t - off] : 0;
        __syncthreads();
        part[t] += u;
        __syncthreads();
    }
    int run = part[t] - sum;  // exclusive prefix
    for (int j = 0; j < CH; ++j) {
        int idx = base + j;
        if (idx < N_NODES) {
            row_start[idx] = run;
            cursor[idx] = run;
            run += deg[idx];
        }
    }
    if (t == 1023) row_start[N_NODES] = part[1023];
}

__global__ void scatter_kernel(const int* __restrict__ src, const int* __restrict__ dst,
                               const int* __restrict__ rel, int* __restrict__ cursor,
                               int* __restrict__ csr_pack) {
    int e = blockIdx.x * 256 + threadIdx.x;
    if (e < N_EDGES) {
        int d = dst[e];
        int p = atomicAdd(&cursor[d], 1);
        csr_pack[p] = src[e] | (rel[e] << 16);   // src < 2^16, rel < 2^10
    }
}

__global__ void tail_kernel(const void* __restrict__ relations, void* __restrict__ out,
                            const int* __restrict__ flag) {
    int i = blockIdx.x * 256 + threadIdx.x;
    if (i >= N_REL * F_DIM) return;
    int f32 = flag[0];
    float v = loadIn(relations, i, f32);
    size_t o = (size_t)N_NODES * F_DIM + i;
    if (f32) ((float*)out)[o] = v;
    else     ((unsigned short*)out)[o] = f2bf(v);
}

// ---------------- GEMM: out[M x Nout] = A[M x 128] @ B[128 x Nout] + bias ----------------
// 128x128 C tile, 4 waves of 64x64, K staged in two BK=64 halves (LDS 36.9 KB).
// MFMA 16x16x32 bf16: A[m=lane&15][k=quad*8+j], B[k=quad*8+j][n=lane&15],
// C/D: col=lane&15, row=quad*4+reg.

__launch_bounds__(256, 2)
__global__ void gemm_kernel(const void* __restrict__ A, int a_input, int M,
                            const void* __restrict__ B, size_t b_off,
                            const void* __restrict__ bias, size_t bias_off,
                            void* __restrict__ out, int out_f32, int Nout,
                            const int* __restrict__ flag) {
    __shared__ __align__(16) short As[128][72];  // stride 72 shorts = 36 words == 4 (mod 32): 2-way max
    __shared__ __align__(16) short Bt[128][72];  // B transposed: Bt[n][k_local]
    int f32 = flag[0];
    int a_f32 = a_input ? f32 : 0;
    int m0 = blockIdx.x * 128, n0 = blockIdx.y * 128;
    int t = threadIdx.x;

    int wave = t >> 6, lane = t & 63;
    int wm = (wave >> 1) * 64, wn = (wave & 1) * 64;
    int r16 = lane & 15, quad = lane >> 4;

    floatx4 acc[4][4];
    for (int mi = 0; mi < 4; ++mi)
        for (int ni = 0; ni < 4; ++ni)
            acc[mi][ni] = (floatx4){0.f, 0.f, 0.f, 0.f};

    for (int half = 0; half < 2; ++half) {
        if (half) __syncthreads();  // protect LDS from overwrite while half-0 compute in flight
        // stage A: 128 rows x 64 cols; thread t does rows (t>>3)+r*32, col chunk (t&7)*8
        for (int r = 0; r < 4; ++r) {
            int row = (t >> 3) + r * 32;
            int gm = m0 + row;
            int col = half * 64 + (t & 7) * 8;
            short8 v = (short8){0, 0, 0, 0, 0, 0, 0, 0};
            if (gm < M) {
                size_t idx = (size_t)gm * F_DIM + col;
                if (a_f32) {
                    const float* Af = (const float*)A;
                    for (int q = 0; q < 8; ++q) v[q] = (short)f2bf(Af[idx + q]);
                } else {
                    v = *(const short8*)((const unsigned short*)A + idx);
                }
            }
            *(short8*)&As[row][(t & 7) * 8] = v;
        }
        // stage B transposed: 64 k-rows x 128 n-cols; 1024 chunks of 8, 4 per thread
        for (int j = 0; j < 4; ++j) {
            int c = t + j * 256;
            int klocal = c >> 4;        // 0..63
            int nloc = (c & 15) * 8;    // 0..120
            size_t idx = b_off + (size_t)(half * 64 + klocal) * Nout + n0 + nloc;
            unsigned short tmp[8];
            if (f32) {
                const float* Bf = (const float*)B;
                for (int q = 0; q < 8; ++q) tmp[q] = f2bf(Bf[idx + q]);
            } else {
                *(short8*)tmp = *(const short8*)((const unsigned short*)B + idx);
            }
            for (int q = 0; q < 8; ++q) Bt[nloc + q][klocal] = (short)tmp[q];
        }
        __syncthreads();

        for (int kk = 0; kk < 2; ++kk) {
            short8 a[4], b[4];
            for (int mi = 0; mi < 4; ++mi)
                a[mi] = *(const short8*)&As[wm + mi * 16 + r16][kk * 32 + quad * 8];
            for (int ni = 0; ni < 4; ++ni)
                b[ni] = *(const short8*)&Bt[wn + ni * 16 + r16][kk * 32 + quad * 8];
            for (int mi = 0; mi < 4; ++mi)
                for (int ni = 0; ni < 4; ++ni)
                    acc[mi][ni] = __builtin_amdgcn_mfma_f32_16x16x32_bf16(a[mi], b[ni], acc[mi][ni], 0, 0, 0);
        }
    }

    for (int mi = 0; mi < 4; ++mi) {
        for (int ni = 0; ni < 4; ++ni) {
            int col = n0 + wn + ni * 16 + r16;
            float bv = bias ? loadIn(bias, bias_off + col, f32) : 0.f;
            for (int r = 0; r < 4; ++r) {
                int row = m0 + wm + mi * 16 + quad * 4 + r;
                if (row < M) {
                    float v = acc[mi][ni][r] + bv;
                    if (out_f32) ((float*)out)[(size_t)row * Nout + col] = v;
                    else         ((unsigned short*)out)[(size_t)row * Nout + col] = f2bf(v);
                }
            }
        }
    }
}

// ---------------- edge scoring + segment softmax + aggregation + head mean ----------------

__launch_bounds__(256)
__global__ void edge_kernel(const unsigned short* __restrict__ xl,
                            const unsigned short* __restrict__ xr,
                            const float* __restrict__ re,
                            const int* __restrict__ row_start,
                            const int* __restrict__ csr_pack,
                            const void* __restrict__ att, size_t att_off,
                            const void* __restrict__ bias, size_t bias_off,
                            void* __restrict__ hout, int final_layer,
                            const int* __restrict__ flag) {
    int f32 = flag[0];
    int i = blockIdx.x;
    int h = threadIdx.x >> 6;
    int lane = threadIdx.x & 63;
    int base = h * F_DIM + lane;

    auto ld = [](const unsigned short* p, size_t idx) -> float {
        union { unsigned int u; float f; } c;
        c.u = ((unsigned int)p[idx]) << 16;
        return c.f;
    };

    float xr0 = ld(xr, (size_t)i * HC + base);
    float xr1 = ld(xr, (size_t)i * HC + base + 64);
    float a0 = loadIn(att, att_off + h * F_DIM + lane, f32);
    float a1 = loadIn(att, att_off + h * F_DIM + lane + 64, f32);

    // self-loop first: src = i, edge attr = mean row (N_REL)
    float xs0 = ld(xl, (size_t)i * HC + base);
    float xs1 = ld(xl, (size_t)i * HC + base + 64);
    float t0 = xs0 + xr0 + re[(size_t)N_REL * HC + base];
    float t1 = xs1 + xr1 + re[(size_t)N_REL * HC + base + 64];
    t0 = (t0 > 0.f) ? t0 : NEG_SLOPE * t0;
    t1 = (t1 > 0.f) ? t1 : NEG_SLOPE * t1;
    float m = t0 * a0 + t1 * a1;
    for (int off = 32; off; off >>= 1) m += __shfl_xor(m, off);
    float s = 1.f, acc0 = xs0, acc1 = xs1;

    int e0 = row_start[i], e1 = row_start[i + 1];
    if (e0 < 0) e0 = 0;
    if (e1 > N_EDGES) e1 = N_EDGES;
    if (e1 < e0) e1 = e0;
    for (int e = e0; e < e1; ++e) {
        int pk = csr_pack[e];
        int src = pk & 0xFFFF;
        int rrow = (pk >> 16) & 0x3FF;
        if (src >= N_NODES) src = 0;           // defensive: finite-wrong, not NaN
        if (rrow > N_REL) rrow = N_REL;
        float xl0 = ld(xl, (size_t)src * HC + base);
        float xl1 = ld(xl, (size_t)src * HC + base + 64);
        float u0 = xl0 + xr0 + re[(size_t)rrow * HC + base];
        float u1 = xl1 + xr1 + re[(size_t)rrow * HC + base + 64];
        u0 = (u0 > 0.f) ? u0 : NEG_SLOPE * u0;
        u1 = (u1 > 0.f) ? u1 : NEG_SLOPE * u1;
        float part = u0 * a0 + u1 * a1;
        for (int off = 32; off; off >>= 1) part += __shfl_xor(part, off);
        float mn = fmaxf(m, part);
        float sc = __expf(m - mn);
        float p  = __expf(part - mn);
        s = s * sc + p;
        acc0 = acc0 * sc + p * xl0;
        acc1 = acc1 * sc + p * xl1;
        m = mn;
    }

    float inv = 1.f / s;
    __shared__ float lsum[N_HEAD][F_DIM];
    lsum[h][lane]      = acc0 * inv;
    lsum[h][lane + 64] = acc1 * inv;
    __syncthreads();
    if (threadIdx.x < F_DIM) {
        int c = threadIdx.x;
        float v = (lsum[0][c] + lsum[1][c] + lsum[2][c] + lsum[3][c]) * 0.25f
                + loadIn(bias, bias_off + c, f32);
        size_t o = (size_t)i * F_DIM + c;
        if (final_layer && f32) ((float*)hout)[o] = v;
        else                    ((unsigned short*)hout)[o] = f2bf(v);
    }
}

// ---------------- launch ----------------

extern "C" void kernel_launch(void* const* d_in, const int* in_sizes, int n_in,
                              void* d_out, int out_size, void* d_ws, size_t ws_size,
                              hipStream_t stream) {
    const void* x          = d_in[0];
    const int*  edge_index = (const int*)d_in[1];
    const void* relations  = d_in[2];
    const int*  rel_index  = (const int*)d_in[3];
    const void* Wl         = d_in[4];
    const void* bl         = d_in[5];
    const void* Wr         = d_in[6];
    const void* br         = d_in[7];
    const void* We         = d_in[8];
    const void* att        = d_in[9];
    const void* bias       = d_in[10];

    char* ws = (char*)d_ws;
    size_t off = 0;
    auto alloc = [&](size_t bytes) -> void* {
        void* p = ws + off;
        off = (off + bytes + 255) & ~(size_t)255;
        return p;
    };
    int*            flag     = (int*)alloc(4);
    int*            deg      = (int*)alloc(N_NODES * 4);
    int*            row_start= (int*)alloc((N_NODES + 1) * 4);
    int*            cursor   = (int*)alloc(N_NODES * 4);
    int*            rcount   = (int*)alloc(N_REL * 4);
    float*          ea_mean  = (float*)alloc(F_DIM * 4);
    int*            csr_pack = (int*)alloc(N_EDGES * 4);
    unsigned short* rel_ext  = (unsigned short*)alloc((size_t)REL_EXT_ROWS * F_DIM * 2);
    float*          re       = (float*)alloc((size_t)REL_EXT_ROWS * HC * 4);
    unsigned short* hbuf     = (unsigned short*)alloc((size_t)N_NODES * F_DIM * 2);
    unsigned short* xl       = (unsigned short*)alloc((size_t)N_NODES * HC * 2);
    unsigned short* xr       = (unsigned short*)alloc((size_t)N_NODES * HC * 2);
    // total ~49.4 MB

    const int* esrc = edge_index;
    const int* edst = edge_index + N_EDGES;

    detect_kernel<<<1, 64, 0, stream>>>((const unsigned short*)x, flag);
    hipMemsetAsync(rcount, 0, N_REL * 4, stream);
    hipMemsetAsync(deg, 0, N_NODES * 4, stream);
    hist_kernel<<<(N_EDGES + 255) / 256, 256, 0, stream>>>(edst, rel_index, deg, rcount);
    ea_mean_kernel<<<1, 128, 0, stream>>>(rcount, relations, ea_mean, flag);
    relext_kernel<<<(REL_EXT_ROWS * F_DIM + 255) / 256, 256, 0, stream>>>(relations, ea_mean, rel_ext, flag);
    scan_kernel<<<1, 1024, 0, stream>>>(deg, row_start, cursor);
    scatter_kernel<<<(N_EDGES + 255) / 256, 256, 0, stream>>>(esrc, edst, rel_index, cursor, csr_pack);
    tail_kernel<<<(N_REL * F_DIM + 255) / 256, 256, 0, stream>>>(relations, d_out, flag);

    const void* hin = x;
    int a_input = 1;
    for (int l = 0; l < N_LAYERS; ++l) {
        dim3 gN((N_NODES + 127) / 128, HC / 128);       // 157 x 4
        gemm_kernel<<<gN, 256, 0, stream>>>(hin, a_input, N_NODES,
                                            Wl, (size_t)l * F_DIM * HC,
                                            bl, (size_t)l * HC, xl, 0, HC, flag);
        gemm_kernel<<<gN, 256, 0, stream>>>(hin, a_input, N_NODES,
                                            Wr, (size_t)l * F_DIM * HC,
                                            br, (size_t)l * HC, xr, 0, HC, flag);
        dim3 gR((REL_EXT_ROWS + 127) / 128, HC / 128);  // 8 x 4
        gemm_kernel<<<gR, 256, 0, stream>>>(rel_ext, 0, REL_EXT_ROWS,
                                            We, (size_t)l * F_DIM * HC,
                                            nullptr, 0, re, 1, HC, flag);
        int final_layer = (l == N_LAYERS - 1);
        void* hout = final_layer ? d_out : (void*)hbuf;
        edge_kernel<<<N_NODES, 256, 0, stream>>>(xl, xr, re, row_start, csr_pack,
                                                 att, (size_t)l * N_HEAD * F_DIM,
                                                 bias, (size_t)l * F_DIM,
                                                 hout, final_layer, flag);
        hin = hbuf;
        a_input = 0;
    }
}

// Round 4
// 949.574 us; speedup vs baseline: 1.0490x; 1.0490x over previous
//
#include <hip/hip_runtime.h>
#include <hip/hip_bf16.h>

#define N_NODES   20000
#define N_EDGES   100000
#define N_REL     1000
#define F_DIM     128
#define N_HEAD    4
#define HC        512      // N_HEAD * F_DIM
#define HC2       256      // HC/2 (bf16 pairs)
#define N_LAYERS  4
#define REL_EXT_ROWS 1008  // 1000 relations + 1 mean row, padded to mult of 16
#define NEG_SLOPE 0.2f

typedef __attribute__((ext_vector_type(8))) short short8;
typedef __attribute__((ext_vector_type(4))) float floatx4;

// Read input element i as float, regardless of whether inputs are fp32 or bf16.
__device__ __forceinline__ float loadIn(const void* p, size_t i, int f32) {
    if (f32) return ((const float*)p)[i];
    union { unsigned int u; float f; } c;
    c.u = ((unsigned int)((const unsigned short*)p)[i]) << 16;
    return c.f;
}

__device__ __forceinline__ unsigned short f2bf(float v) {
    __hip_bfloat16 b = __float2bfloat16(v);
    return *(unsigned short*)&b;
}

__device__ __forceinline__ void unpack2(unsigned int u, float& lo, float& hi) {
    union { unsigned int u; float f; } a, b;
    a.u = u << 16;          // low  u16 -> channel 2*lane
    b.u = u & 0xFFFF0000u;  // high u16 -> channel 2*lane+1
    lo = a.f; hi = b.f;
}

// ---------------- dtype detection ----------------
__global__ void detect_kernel(const unsigned short* __restrict__ x, int* __restrict__ flag) {
    int t = threadIdx.x;  // 64
    int cnt = 0;
    for (int j = t; j < 256; j += 64) {
        int e = (x[j] >> 7) & 0xFF;
        if (e >= 143) cnt++;   // |v| >= 2^16 or NaN/Inf
    }
    for (int off = 32; off; off >>= 1) cnt += __shfl_xor(cnt, off);
    if (t == 0) flag[0] = (cnt >= 8) ? 1 : 0;
}

// ---------------- preprocessing ----------------

__global__ void hist_kernel(const int* __restrict__ dst, const int* __restrict__ rel,
                            int* __restrict__ deg, int* __restrict__ rcount) {
    int e = blockIdx.x * 256 + threadIdx.x;
    if (e < N_EDGES) {
        atomicAdd(&deg[dst[e]], 1);
        atomicAdd(&rcount[rel[e]], 1);
    }
}

// 125 blocks x 256 threads; block b covers rows b*8..b*8+7, coalesced column reads,
// LDS partial + one fp32 atomicAdd per column per block. ea_mean must be zeroed first.
__global__ void ea_mean_kernel(const int* __restrict__ rcount,
                               const void* __restrict__ relations,
                               float* __restrict__ ea_mean, const int* __restrict__ flag) {
    int f32 = flag[0];
    int b = blockIdx.x;
    int t = threadIdx.x;
    int col = t & 127;
    int rhalf = t >> 7;   // 0 or 1
    float acc = 0.f;
    for (int j = 0; j < 4; ++j) {
        int r = b * 8 + j * 2 + rhalf;
        acc += (float)rcount[r] * loadIn(relations, (size_t)r * F_DIM + col, f32);
    }
    __shared__ float part[256];
    part[t] = acc;
    __syncthreads();
    if (t < 128)
        atomicAdd(&ea_mean[col], (part[t] + part[t + 128]) * (1.f / (float)N_EDGES));
}

__global__ void relext_kernel(const void* __restrict__ relations,
                              const float* __restrict__ ea_mean,
                              unsigned short* __restrict__ rel_ext, const int* __restrict__ flag) {
    int idx = blockIdx.x * 256 + threadIdx.x;
    if (idx >= REL_EXT_ROWS * F_DIM) return;
    int f32 = flag[0];
    int r = idx >> 7;
    int c = idx & 127;
    float v;
    if (r < N_REL)       v = loadIn(relations, idx, f32);
    else if (r == N_REL) v = ea_mean[c];
    else                 v = 0.f;
    rel_ext[idx] = f2bf(v);
}

__global__ void scan_kernel(const int* __restrict__ deg,
                            int* __restrict__ row_start, int* __restrict__ cursor) {
    __shared__ int part[1024];
    int t = threadIdx.x;
    const int CH = (N_NODES + 1023) / 1024;  // 20
    int base = t * CH;
    int sum = 0;
    for (int j = 0; j < CH; ++j) {
        int idx = base + j;
        if (idx < N_NODES) sum += deg[idx];
    }
    part[t] = sum;
    __syncthreads();
    for (int off = 1; off < 1024; off <<= 1) {
        int u = (t >= off) ? part[t - off] : 0;
        __syncthreads();
        part[t] += u;
        __syncthreads();
    }
    int run = part[t] - sum;  // exclusive prefix
    for (int j = 0; j < CH; ++j) {
        int idx = base + j;
        if (idx < N_NODES) {
            row_start[idx] = run;
            cursor[idx] = run;
            run += deg[idx];
        }
    }
    if (t == 1023) row_start[N_NODES] = part[1023];
}

__global__ void scatter_kernel(const int* __restrict__ src, const int* __restrict__ dst,
                               const int* __restrict__ rel, int* __restrict__ cursor,
                               int* __restrict__ csr_pack) {
    int e = blockIdx.x * 256 + threadIdx.x;
    if (e < N_EDGES) {
        int d = dst[e];
        int p = atomicAdd(&cursor[d], 1);
        csr_pack[p] = src[e] | (rel[e] << 16);   // src < 2^16, rel < 2^10
    }
}

__global__ void tail_kernel(const void* __restrict__ relations, void* __restrict__ out,
                            const int* __restrict__ flag) {
    int i = blockIdx.x * 256 + threadIdx.x;
    if (i >= N_REL * F_DIM) return;
    int f32 = flag[0];
    float v = loadIn(relations, i, f32);
    size_t o = (size_t)N_NODES * F_DIM + i;
    if (f32) ((float*)out)[o] = v;
    else     ((unsigned short*)out)[o] = f2bf(v);
}

// ---------------- GEMM: out[M x Nout] = A[M x 128] @ B[128 x Nout] + bias ----------------
// 128x128 C tile, 4 waves of 64x64, K staged in two BK=64 halves (LDS 36.9 KB).
// MFMA 16x16x32 bf16: A[m=lane&15][k=quad*8+j], B[k=quad*8+j][n=lane&15],
// C/D: col=lane&15, row=quad*4+reg.

__launch_bounds__(256, 2)
__global__ void gemm_kernel(const void* __restrict__ A, int a_input, int M,
                            const void* __restrict__ B, size_t b_off,
                            const void* __restrict__ bias, size_t bias_off,
                            void* __restrict__ out, int out_f32, int Nout,
                            const int* __restrict__ flag) {
    __shared__ __align__(16) short As[128][72];
    __shared__ __align__(16) short Bt[128][72];
    int f32 = flag[0];
    int a_f32 = a_input ? f32 : 0;
    int m0 = blockIdx.x * 128, n0 = blockIdx.y * 128;
    int t = threadIdx.x;

    int wave = t >> 6, lane = t & 63;
    int wm = (wave >> 1) * 64, wn = (wave & 1) * 64;
    int r16 = lane & 15, quad = lane >> 4;

    floatx4 acc[4][4];
    for (int mi = 0; mi < 4; ++mi)
        for (int ni = 0; ni < 4; ++ni)
            acc[mi][ni] = (floatx4){0.f, 0.f, 0.f, 0.f};

    for (int half = 0; half < 2; ++half) {
        if (half) __syncthreads();
        for (int r = 0; r < 4; ++r) {
            int row = (t >> 3) + r * 32;
            int gm = m0 + row;
            int col = half * 64 + (t & 7) * 8;
            short8 v = (short8){0, 0, 0, 0, 0, 0, 0, 0};
            if (gm < M) {
                size_t idx = (size_t)gm * F_DIM + col;
                if (a_f32) {
                    const float* Af = (const float*)A;
                    for (int q = 0; q < 8; ++q) v[q] = (short)f2bf(Af[idx + q]);
                } else {
                    v = *(const short8*)((const unsigned short*)A + idx);
                }
            }
            *(short8*)&As[row][(t & 7) * 8] = v;
        }
        for (int j = 0; j < 4; ++j) {
            int c = t + j * 256;
            int klocal = c >> 4;
            int nloc = (c & 15) * 8;
            size_t idx = b_off + (size_t)(half * 64 + klocal) * Nout + n0 + nloc;
            unsigned short tmp[8];
            if (f32) {
                const float* Bf = (const float*)B;
                for (int q = 0; q < 8; ++q) tmp[q] = f2bf(Bf[idx + q]);
            } else {
                *(short8*)tmp = *(const short8*)((const unsigned short*)B + idx);
            }
            for (int q = 0; q < 8; ++q) Bt[nloc + q][klocal] = (short)tmp[q];
        }
        __syncthreads();

        for (int kk = 0; kk < 2; ++kk) {
            short8 a[4], b[4];
            for (int mi = 0; mi < 4; ++mi)
                a[mi] = *(const short8*)&As[wm + mi * 16 + r16][kk * 32 + quad * 8];
            for (int ni = 0; ni < 4; ++ni)
                b[ni] = *(const short8*)&Bt[wn + ni * 16 + r16][kk * 32 + quad * 8];
            for (int mi = 0; mi < 4; ++mi)
                for (int ni = 0; ni < 4; ++ni)
                    acc[mi][ni] = __builtin_amdgcn_mfma_f32_16x16x32_bf16(a[mi], b[ni], acc[mi][ni], 0, 0, 0);
        }
    }

    for (int mi = 0; mi < 4; ++mi) {
        for (int ni = 0; ni < 4; ++ni) {
            int col = n0 + wn + ni * 16 + r16;
            float bv = bias ? loadIn(bias, bias_off + col, f32) : 0.f;
            for (int r = 0; r < 4; ++r) {
                int row = m0 + wm + mi * 16 + quad * 4 + r;
                if (row < M) {
                    float v = acc[mi][ni][r] + bv;
                    if (out_f32) ((float*)out)[(size_t)row * Nout + col] = v;
                    else         ((unsigned short*)out)[(size_t)row * Nout + col] = f2bf(v);
                }
            }
        }
    }
}

// ---------------- edge scoring + segment softmax + aggregation + head mean ----------------
// One block per dst node; wave h = head h; lane owns channels (2*lane, 2*lane+1):
// one 4B uint load per xl/re row per lane instead of 2 scalar loads each.

__launch_bounds__(256)
__global__ void edge_kernel(const unsigned int* __restrict__ xl2,
                            const unsigned int* __restrict__ xr2,
                            const unsigned int* __restrict__ re2,
                            const int* __restrict__ row_start,
                            const int* __restrict__ csr_pack,
                            const void* __restrict__ att, size_t att_off,
                            const void* __restrict__ bias, size_t bias_off,
                            void* __restrict__ hout, int final_layer,
                            const int* __restrict__ flag) {
    int f32 = flag[0];
    int i = blockIdx.x;
    int h = threadIdx.x >> 6;
    int lane = threadIdx.x & 63;
    int pidx = h * 64 + lane;   // pair index within HC2

    float xr0, xr1; unpack2(xr2[(size_t)i * HC2 + pidx], xr0, xr1);
    float a0 = loadIn(att, att_off + h * F_DIM + 2 * lane, f32);
    float a1 = loadIn(att, att_off + h * F_DIM + 2 * lane + 1, f32);
    float er0, er1; unpack2(re2[(size_t)N_REL * HC2 + pidx], er0, er1);

    // self-loop first: src = i, edge attr = mean row (N_REL)
    float xs0, xs1; unpack2(xl2[(size_t)i * HC2 + pidx], xs0, xs1);
    float t0 = xs0 + xr0 + er0;
    float t1 = xs1 + xr1 + er1;
    t0 = (t0 > 0.f) ? t0 : NEG_SLOPE * t0;
    t1 = (t1 > 0.f) ? t1 : NEG_SLOPE * t1;
    float m = t0 * a0 + t1 * a1;
    for (int off = 32; off; off >>= 1) m += __shfl_xor(m, off);
    float s = 1.f, acc0 = xs0, acc1 = xs1;

    int e0 = row_start[i], e1 = row_start[i + 1];
    if (e0 < 0) e0 = 0;
    if (e1 > N_EDGES) e1 = N_EDGES;
    if (e1 < e0) e1 = e0;

    int pk = (e0 < e1) ? csr_pack[e0] : 0;
    for (int e = e0; e < e1; ++e) {
        int pknext = (e + 1 < e1) ? csr_pack[e + 1] : 0;
        int src = pk & 0xFFFF;
        int rrow = (pk >> 16) & 0x3FF;
        if (src >= N_NODES) src = 0;
        if (rrow > N_REL) rrow = N_REL;
        float xl0, xl1; unpack2(xl2[(size_t)src * HC2 + pidx], xl0, xl1);
        float ee0, ee1; unpack2(re2[(size_t)rrow * HC2 + pidx], ee0, ee1);
        float u0 = xl0 + xr0 + ee0;
        float u1 = xl1 + xr1 + ee1;
        u0 = (u0 > 0.f) ? u0 : NEG_SLOPE * u0;
        u1 = (u1 > 0.f) ? u1 : NEG_SLOPE * u1;
        float part = u0 * a0 + u1 * a1;
        for (int off = 32; off; off >>= 1) part += __shfl_xor(part, off);
        float mn = fmaxf(m, part);
        float sc = __expf(m - mn);
        float p  = __expf(part - mn);
        s = s * sc + p;
        acc0 = acc0 * sc + p * xl0;
        acc1 = acc1 * sc + p * xl1;
        m = mn;
        pk = pknext;
    }

    float inv = 1.f / s;
    __shared__ float lsum[N_HEAD][F_DIM];
    lsum[h][2 * lane]     = acc0 * inv;
    lsum[h][2 * lane + 1] = acc1 * inv;
    __syncthreads();
    if (threadIdx.x < F_DIM) {
        int c = threadIdx.x;
        float v = (lsum[0][c] + lsum[1][c] + lsum[2][c] + lsum[3][c]) * 0.25f
                + loadIn(bias, bias_off + c, f32);
        size_t o = (size_t)i * F_DIM + c;
        if (final_layer && f32) ((float*)hout)[o] = v;
        else                    ((unsigned short*)hout)[o] = f2bf(v);
    }
}

// ---------------- launch ----------------

extern "C" void kernel_launch(void* const* d_in, const int* in_sizes, int n_in,
                              void* d_out, int out_size, void* d_ws, size_t ws_size,
                              hipStream_t stream) {
    const void* x          = d_in[0];
    const int*  edge_index = (const int*)d_in[1];
    const void* relations  = d_in[2];
    const int*  rel_index  = (const int*)d_in[3];
    const void* Wl         = d_in[4];
    const void* bl         = d_in[5];
    const void* Wr         = d_in[6];
    const void* br         = d_in[7];
    const void* We         = d_in[8];
    const void* att        = d_in[9];
    const void* bias       = d_in[10];

    char* ws = (char*)d_ws;
    size_t off = 0;
    auto alloc = [&](size_t bytes) -> void* {
        void* p = ws + off;
        off = (off + bytes + 255) & ~(size_t)255;
        return p;
    };
    int*            flag     = (int*)alloc(4);
    int*            deg      = (int*)alloc(N_NODES * 4);
    int*            row_start= (int*)alloc((N_NODES + 1) * 4);
    int*            cursor   = (int*)alloc(N_NODES * 4);
    int*            rcount   = (int*)alloc(N_REL * 4);
    float*          ea_mean  = (float*)alloc(F_DIM * 4);
    int*            csr_pack = (int*)alloc(N_EDGES * 4);
    unsigned short* rel_ext  = (unsigned short*)alloc((size_t)REL_EXT_ROWS * F_DIM * 2);
    unsigned short* re       = (unsigned short*)alloc((size_t)REL_EXT_ROWS * HC * 2);
    unsigned short* hbuf     = (unsigned short*)alloc((size_t)N_NODES * F_DIM * 2);
    unsigned short* xl       = (unsigned short*)alloc((size_t)N_NODES * HC * 2);
    unsigned short* xr       = (unsigned short*)alloc((size_t)N_NODES * HC * 2);
    // total ~47 MB

    const int* esrc = edge_index;
    const int* edst = edge_index + N_EDGES;

    detect_kernel<<<1, 64, 0, stream>>>((const unsigned short*)x, flag);
    hipMemsetAsync(rcount, 0, N_REL * 4, stream);
    hipMemsetAsync(deg, 0, N_NODES * 4, stream);
    hipMemsetAsync(ea_mean, 0, F_DIM * 4, stream);
    hist_kernel<<<(N_EDGES + 255) / 256, 256, 0, stream>>>(edst, rel_index, deg, rcount);
    ea_mean_kernel<<<N_REL / 8, 256, 0, stream>>>(rcount, relations, ea_mean, flag);
    relext_kernel<<<(REL_EXT_ROWS * F_DIM + 255) / 256, 256, 0, stream>>>(relations, ea_mean, rel_ext, flag);
    scan_kernel<<<1, 1024, 0, stream>>>(deg, row_start, cursor);
    scatter_kernel<<<(N_EDGES + 255) / 256, 256, 0, stream>>>(esrc, edst, rel_index, cursor, csr_pack);
    tail_kernel<<<(N_REL * F_DIM + 255) / 256, 256, 0, stream>>>(relations, d_out, flag);

    const void* hin = x;
    int a_input = 1;
    for (int l = 0; l < N_LAYERS; ++l) {
        dim3 gN((N_NODES + 127) / 128, HC / 128);       // 157 x 4
        gemm_kernel<<<gN, 256, 0, stream>>>(hin, a_input, N_NODES,
                                            Wl, (size_t)l * F_DIM * HC,
                                            bl, (size_t)l * HC, xl, 0, HC, flag);
        gemm_kernel<<<gN, 256, 0, stream>>>(hin, a_input, N_NODES,
                                            Wr, (size_t)l * F_DIM * HC,
                                            br, (size_t)l * HC, xr, 0, HC, flag);
        dim3 gR((REL_EXT_ROWS + 127) / 128, HC / 128);  // 8 x 4
        gemm_kernel<<<gR, 256, 0, stream>>>(rel_ext, 0, REL_EXT_ROWS,
                                            We, (size_t)l * F_DIM * HC,
                                            nullptr, 0, re, 0, HC, flag);
        int final_layer = (l == N_LAYERS - 1);
        void* hout = final_layer ? d_out : (void*)hbuf;
        edge_kernel<<<N_NODES, 256, 0, stream>>>((const unsigned int*)xl, (const unsigned int*)xr,
                                                 (const unsigned int*)re, row_start, csr_pack,
                                                 att, (size_t)l * N_HEAD * F_DIM,
                                                 bias, (size_t)l * F_DIM,
                                                 hout, final_layer, flag);
        hin = hbuf;
        a_input = 0;
    }
}

// Round 6
// 869.533 us; speedup vs baseline: 1.1456x; 1.0921x over previous
//
#include <hip/hip_runtime.h>
#include <hip/hip_bf16.h>

#define N_NODES   20000
#define N_EDGES   100000
#define N_REL     1000
#define F_DIM     128
#define N_HEAD    4
#define HC        512      // N_HEAD * F_DIM
#define HC2       256      // HC/2 (bf16 pairs)
#define N_LAYERS  4
#define REL_EXT_ROWS 1008  // 1000 relations + 1 mean row
#define NEG_SLOPE 0.2f

typedef __attribute__((ext_vector_type(8))) short short8;
typedef __attribute__((ext_vector_type(4))) float floatx4;

__device__ __forceinline__ float loadIn(const void* p, size_t i, int f32) {
    if (f32) return ((const float*)p)[i];
    union { unsigned int u; float f; } c;
    c.u = ((unsigned int)((const unsigned short*)p)[i]) << 16;
    return c.f;
}

__device__ __forceinline__ unsigned short f2bf(float v) {
    __hip_bfloat16 b = __float2bfloat16(v);
    return *(unsigned short*)&b;
}

__device__ __forceinline__ void unpack2(unsigned int u, float& lo, float& hi) {
    union { unsigned int u; float f; } a, b;
    a.u = u << 16;
    b.u = u & 0xFFFF0000u;
    lo = a.f; hi = b.f;
}

// ---------------- dtype detection ----------------
__global__ void detect_kernel(const unsigned short* __restrict__ x, int* __restrict__ flag) {
    int t = threadIdx.x;  // 64
    int cnt = 0;
    for (int j = t; j < 256; j += 64) {
        int e = (x[j] >> 7) & 0xFF;
        if (e >= 143) cnt++;
    }
    for (int off = 32; off; off >>= 1) cnt += __shfl_xor(cnt, off);
    if (t == 0) flag[0] = (cnt >= 8) ? 1 : 0;
}

// ---------------- preprocessing ----------------

__global__ void hist_kernel(const int* __restrict__ dst, const int* __restrict__ rel,
                            int* __restrict__ deg, int* __restrict__ rcount) {
    int e = blockIdx.x * 256 + threadIdx.x;
    if (e < N_EDGES) {
        atomicAdd(&deg[dst[e]], 1);
        atomicAdd(&rcount[rel[e]], 1);
    }
}

__global__ void ea_mean_kernel(const int* __restrict__ rcount,
                               const void* __restrict__ relations,
                               float* __restrict__ ea_mean, const int* __restrict__ flag) {
    int f32 = flag[0];
    int b = blockIdx.x;
    int t = threadIdx.x;
    int col = t & 127;
    int rhalf = t >> 7;
    float acc = 0.f;
    for (int j = 0; j < 4; ++j) {
        int r = b * 8 + j * 2 + rhalf;
        acc += (float)rcount[r] * loadIn(relations, (size_t)r * F_DIM + col, f32);
    }
    __shared__ float part[256];
    part[t] = acc;
    __syncthreads();
    if (t < 128)
        atomicAdd(&ea_mean[col], (part[t] + part[t + 128]) * (1.f / (float)N_EDGES));
}

__global__ void relext_kernel(const void* __restrict__ relations,
                              const float* __restrict__ ea_mean,
                              unsigned short* __restrict__ rel_ext, const int* __restrict__ flag) {
    int idx = blockIdx.x * 256 + threadIdx.x;
    if (idx >= REL_EXT_ROWS * F_DIM) return;
    int f32 = flag[0];
    int r = idx >> 7;
    int c = idx & 127;
    float v;
    if (r < N_REL)       v = loadIn(relations, idx, f32);
    else if (r == N_REL) v = ea_mean[c];
    else                 v = 0.f;
    rel_ext[idx] = f2bf(v);
}

__global__ void scan_kernel(const int* __restrict__ deg,
                            int* __restrict__ row_start, int* __restrict__ cursor) {
    __shared__ int part[1024];
    int t = threadIdx.x;
    const int CH = (N_NODES + 1023) / 1024;  // 20
    int base = t * CH;
    int sum = 0;
    for (int j = 0; j < CH; ++j) {
        int idx = base + j;
        if (idx < N_NODES) sum += deg[idx];
    }
    part[t] = sum;
    __syncthreads();
    for (int off = 1; off < 1024; off <<= 1) {
        int u = (t >= off) ? part[t - off] : 0;
        __syncthreads();
        part[t] += u;
        __syncthreads();
    }
    int run = part[t] - sum;
    for (int j = 0; j < CH; ++j) {
        int idx = base + j;
        if (idx < N_NODES) {
            row_start[idx] = run;
            cursor[idx] = run;
            run += deg[idx];
        }
    }
    if (t == 1023) row_start[N_NODES] = part[1023];
}

__global__ void scatter_kernel(const int* __restrict__ src, const int* __restrict__ dst,
                               const int* __restrict__ rel, int* __restrict__ cursor,
                               int* __restrict__ csr_pack) {
    int e = blockIdx.x * 256 + threadIdx.x;
    if (e < N_EDGES) {
        int d = dst[e];
        int p = atomicAdd(&cursor[d], 1);
        csr_pack[p] = src[e] | (rel[e] << 16);
    }
}

__global__ void tail_kernel(const void* __restrict__ relations, void* __restrict__ out,
                            const int* __restrict__ flag) {
    int i = blockIdx.x * 256 + threadIdx.x;
    if (i >= N_REL * F_DIM) return;
    int f32 = flag[0];
    float v = loadIn(relations, i, f32);
    size_t o = (size_t)N_NODES * F_DIM + i;
    if (f32) ((float*)out)[o] = v;
    else     ((unsigned short*)out)[o] = f2bf(v);
}

// ---------------- weight transpose: W[l][128 k][512 n] -> Wt[mat][512 n][128 k] bf16 ----------------
__global__ void w_transpose_kernel(const void* __restrict__ Wl, const void* __restrict__ Wr,
                                   const void* __restrict__ We,
                                   unsigned short* __restrict__ Wt, const int* __restrict__ flag) {
    int f32 = flag[0];
    int k0 = blockIdx.x * 64;
    int n0 = blockIdx.y * 64;
    int mat = blockIdx.z;
    const void* src = (mat < 4) ? Wl : (mat < 8 ? Wr : We);
    size_t base = (size_t)(mat & 3) * F_DIM * HC;
    unsigned short* dst = Wt + (size_t)mat * HC * F_DIM;
    __shared__ float T[64][65];
    int t = threadIdx.x;
    int r = t >> 2, cq = t & 3;
    for (int j = 0; j < 16; ++j) {
        int n = cq * 16 + j;
        T[n][r] = loadIn(src, base + (size_t)(k0 + r) * HC + n0 + n, f32);
    }
    __syncthreads();
    for (int j = 0; j < 16; ++j) {
        int k = cq * 16 + j;
        dst[(size_t)(n0 + r) * F_DIM + k0 + k] = f2bf(T[r][k]);
    }
}

// ---------------- fused projection GEMM ----------------
// out[M x 512] = A[M x 128] @ W (+bias), one or two weight matrices per launch.
// A staged ONCE into As[128][136] (full K, stride 136 => 2-way bank alias, free).
// Per n-tile (128 cols) and k-half (64), stage Bt[128][72] from pre-transposed
// bf16 Wt[n][k] (coalesced 16B reads, conflict-free b128 LDS writes), then 2 MFMA k-steps.
// MFMA 16x16x32 bf16; C/D: col=lane&15, row=quad*4+reg.
__launch_bounds__(256, 2)
__global__ void proj_kernel(const void* __restrict__ A, int a_input, int M,
                            const unsigned short* __restrict__ Wt0,
                            const unsigned short* __restrict__ Wt1,
                            const void* __restrict__ bias0, size_t b0_off,
                            const void* __restrict__ bias1, size_t b1_off,
                            unsigned short* __restrict__ out0,
                            unsigned short* __restrict__ out1,
                            int ntiles, const int* __restrict__ flag) {
    __shared__ __align__(16) short As[128][136];  // 34.8 KB, full K=128
    __shared__ __align__(16) short Bt[128][72];   // 18.4 KB, half K=64
    int f32 = flag[0];
    int a_f32 = a_input ? f32 : 0;
    int m0 = blockIdx.x * 128;
    int t = threadIdx.x;
    int colc = (t & 15) * 8;   // 0..120, valid for stride-136 As

    // stage A once: 128 rows x 128 K
    for (int r = 0; r < 8; ++r) {
        int row = (t >> 4) + r * 16;
        int gm = m0 + row;
        short8 v = (short8){0, 0, 0, 0, 0, 0, 0, 0};
        if (gm < M) {
            size_t idx = (size_t)gm * F_DIM + colc;
            if (a_f32) {
                const float* Af = (const float*)A;
                for (int q = 0; q < 8; ++q) v[q] = (short)f2bf(Af[idx + q]);
            } else {
                v = *(const short8*)((const unsigned short*)A + idx);
            }
        }
        *(short8*)&As[row][colc] = v;
    }

    int wave = t >> 6, lane = t & 63;
    int wm = (wave >> 1) * 64, wn = (wave & 1) * 64;
    int r16 = lane & 15, quad = lane >> 4;

    for (int nt = 0; nt < ntiles; ++nt) {
        const unsigned short* Wt = (nt < 4) ? Wt0 : Wt1;
        int n0 = (nt & 3) * 128;

        floatx4 acc[4][4];
        for (int mi = 0; mi < 4; ++mi)
            for (int ni = 0; ni < 4; ++ni)
                acc[mi][ni] = (floatx4){0.f, 0.f, 0.f, 0.f};

        for (int half = 0; half < 2; ++half) {
            __syncthreads();   // prev Bt reads retired (and As writes visible at nt=0)
            // stage Bt[nl][k] = Wt[n0+nl][half*64+k]; thread t: 4 short8 chunks
            for (int j = 0; j < 4; ++j) {
                int c = t + j * 256;        // 0..1023
                int nl = c >> 3;            // 0..127
                int kc = (c & 7) * 8;       // 0..56
                *(short8*)&Bt[nl][kc] =
                    *(const short8*)(Wt + (size_t)(n0 + nl) * F_DIM + half * 64 + kc);
            }
            __syncthreads();

            for (int kk = 0; kk < 2; ++kk) {
                short8 a[4], b[4];
                for (int mi = 0; mi < 4; ++mi)
                    a[mi] = *(const short8*)&As[wm + mi * 16 + r16][half * 64 + kk * 32 + quad * 8];
                for (int ni = 0; ni < 4; ++ni)
                    b[ni] = *(const short8*)&Bt[wn + ni * 16 + r16][kk * 32 + quad * 8];
                for (int mi = 0; mi < 4; ++mi)
                    for (int ni = 0; ni < 4; ++ni)
                        acc[mi][ni] = __builtin_amdgcn_mfma_f32_16x16x32_bf16(a[mi], b[ni], acc[mi][ni], 0, 0, 0);
            }
        }

        const void* bias = (nt < 4) ? bias0 : bias1;
        size_t boff = (nt < 4) ? b0_off : b1_off;
        unsigned short* out = (nt < 4) ? out0 : out1;
        for (int mi = 0; mi < 4; ++mi) {
            for (int ni = 0; ni < 4; ++ni) {
                int col = n0 + wn + ni * 16 + r16;
                float bv = bias ? loadIn(bias, boff + col, f32) : 0.f;
                for (int r = 0; r < 4; ++r) {
                    int row = m0 + wm + mi * 16 + quad * 4 + r;
                    if (row < M)
                        out[(size_t)row * HC + col] = f2bf(acc[mi][ni][r] + bv);
                }
            }
        }
    }
}

// ---------------- edge scoring + segment softmax + aggregation + head mean ----------------
__launch_bounds__(256)
__global__ void edge_kernel(const unsigned int* __restrict__ xl2,
                            const unsigned int* __restrict__ xr2,
                            const unsigned int* __restrict__ re2,
                            const int* __restrict__ row_start,
                            const int* __restrict__ csr_pack,
                            const void* __restrict__ att, size_t att_off,
                            const void* __restrict__ bias, size_t bias_off,
                            void* __restrict__ hout, int final_layer,
                            const int* __restrict__ flag) {
    int f32 = flag[0];
    int i = blockIdx.x;
    int h = threadIdx.x >> 6;
    int lane = threadIdx.x & 63;
    int pidx = h * 64 + lane;

    float xr0, xr1; unpack2(xr2[(size_t)i * HC2 + pidx], xr0, xr1);
    float a0 = loadIn(att, att_off + h * F_DIM + 2 * lane, f32);
    float a1 = loadIn(att, att_off + h * F_DIM + 2 * lane + 1, f32);
    float er0, er1; unpack2(re2[(size_t)N_REL * HC2 + pidx], er0, er1);

    // self-loop first
    float xs0, xs1; unpack2(xl2[(size_t)i * HC2 + pidx], xs0, xs1);
    float t0 = xs0 + xr0 + er0;
    float t1 = xs1 + xr1 + er1;
    t0 = (t0 > 0.f) ? t0 : NEG_SLOPE * t0;
    t1 = (t1 > 0.f) ? t1 : NEG_SLOPE * t1;
    float m = t0 * a0 + t1 * a1;
    for (int off = 32; off; off >>= 1) m += __shfl_xor(m, off);
    float s = 1.f, acc0 = xs0, acc1 = xs1;

    int e0 = row_start[i], e1 = row_start[i + 1];
    if (e0 < 0) e0 = 0;
    if (e1 > N_EDGES) e1 = N_EDGES;
    if (e1 < e0) e1 = e0;

    unsigned int xlv = 0, rev = 0;
    if (e0 < e1) {
        int pk = csr_pack[e0];
        int src = pk & 0xFFFF;  if (src >= N_NODES) src = 0;
        int rr  = (pk >> 16) & 0x3FF; if (rr > N_REL) rr = N_REL;
        xlv = xl2[(size_t)src * HC2 + pidx];
        rev = re2[(size_t)rr * HC2 + pidx];
    }
    for (int e = e0; e < e1; ++e) {
        unsigned int xlvn = 0, revn = 0;
        if (e + 1 < e1) {
            int pkn = csr_pack[e + 1];
            int sn = pkn & 0xFFFF;  if (sn >= N_NODES) sn = 0;
            int rn = (pkn >> 16) & 0x3FF; if (rn > N_REL) rn = N_REL;
            xlvn = xl2[(size_t)sn * HC2 + pidx];
            revn = re2[(size_t)rn * HC2 + pidx];
        }
        float xl0, xl1; unpack2(xlv, xl0, xl1);
        float ee0, ee1; unpack2(rev, ee0, ee1);
        float u0 = xl0 + xr0 + ee0;
        float u1 = xl1 + xr1 + ee1;
        u0 = (u0 > 0.f) ? u0 : NEG_SLOPE * u0;
        u1 = (u1 > 0.f) ? u1 : NEG_SLOPE * u1;
        float part = u0 * a0 + u1 * a1;
        for (int off = 32; off; off >>= 1) part += __shfl_xor(part, off);
        float mn = fmaxf(m, part);
        float sc = __expf(m - mn);
        float p  = __expf(part - mn);
        s = s * sc + p;
        acc0 = acc0 * sc + p * xl0;
        acc1 = acc1 * sc + p * xl1;
        m = mn;
        xlv = xlvn; rev = revn;
    }

    float inv = 1.f / s;
    __shared__ float lsum[N_HEAD][F_DIM];
    lsum[h][2 * lane]     = acc0 * inv;
    lsum[h][2 * lane + 1] = acc1 * inv;
    __syncthreads();
    if (threadIdx.x < F_DIM) {
        int c = threadIdx.x;
        float v = (lsum[0][c] + lsum[1][c] + lsum[2][c] + lsum[3][c]) * 0.25f
                + loadIn(bias, bias_off + c, f32);
        size_t o = (size_t)i * F_DIM + c;
        if (final_layer && f32) ((float*)hout)[o] = v;
        else                    ((unsigned short*)hout)[o] = f2bf(v);
    }
}

// ---------------- launch ----------------

extern "C" void kernel_launch(void* const* d_in, const int* in_sizes, int n_in,
                              void* d_out, int out_size, void* d_ws, size_t ws_size,
                              hipStream_t stream) {
    const void* x          = d_in[0];
    const int*  edge_index = (const int*)d_in[1];
    const void* relations  = d_in[2];
    const int*  rel_index  = (const int*)d_in[3];
    const void* Wl         = d_in[4];
    const void* bl         = d_in[5];
    const void* Wr         = d_in[6];
    const void* br         = d_in[7];
    const void* We         = d_in[8];
    const void* att        = d_in[9];
    const void* bias       = d_in[10];

    char* ws = (char*)d_ws;
    size_t off = 0;
    auto alloc = [&](size_t bytes) -> void* {
        void* p = ws + off;
        off = (off + bytes + 255) & ~(size_t)255;
        return p;
    };
    int*            flag     = (int*)alloc(4);
    int*            deg      = (int*)alloc(N_NODES * 4);
    int*            row_start= (int*)alloc((N_NODES + 1) * 4);
    int*            cursor   = (int*)alloc(N_NODES * 4);
    int*            rcount   = (int*)alloc(N_REL * 4);
    float*          ea_mean  = (float*)alloc(F_DIM * 4);
    int*            csr_pack = (int*)alloc(N_EDGES * 4);
    unsigned short* rel_ext  = (unsigned short*)alloc((size_t)REL_EXT_ROWS * F_DIM * 2);
    unsigned short* Wt       = (unsigned short*)alloc((size_t)12 * HC * F_DIM * 2);  // 1.57 MB
    unsigned short* re       = (unsigned short*)alloc((size_t)REL_EXT_ROWS * HC * 2);
    unsigned short* hbuf     = (unsigned short*)alloc((size_t)N_NODES * F_DIM * 2);
    unsigned short* xl       = (unsigned short*)alloc((size_t)N_NODES * HC * 2);
    unsigned short* xr       = (unsigned short*)alloc((size_t)N_NODES * HC * 2);
    // total ~49 MB

    const int* esrc = edge_index;
    const int* edst = edge_index + N_EDGES;

    detect_kernel<<<1, 64, 0, stream>>>((const unsigned short*)x, flag);
    hipMemsetAsync(rcount, 0, N_REL * 4, stream);
    hipMemsetAsync(deg, 0, N_NODES * 4, stream);
    hipMemsetAsync(ea_mean, 0, F_DIM * 4, stream);
    hist_kernel<<<(N_EDGES + 255) / 256, 256, 0, stream>>>(edst, rel_index, deg, rcount);
    ea_mean_kernel<<<N_REL / 8, 256, 0, stream>>>(rcount, relations, ea_mean, flag);
    relext_kernel<<<(REL_EXT_ROWS * F_DIM + 255) / 256, 256, 0, stream>>>(relations, ea_mean, rel_ext, flag);
    scan_kernel<<<1, 1024, 0, stream>>>(deg, row_start, cursor);
    scatter_kernel<<<(N_EDGES + 255) / 256, 256, 0, stream>>>(esrc, edst, rel_index, cursor, csr_pack);
    w_transpose_kernel<<<dim3(2, 8, 12), 256, 0, stream>>>(Wl, Wr, We, Wt, flag);
    tail_kernel<<<(N_REL * F_DIM + 255) / 256, 256, 0, stream>>>(relations, d_out, flag);

    const void* hin = x;
    int a_input = 1;
    for (int l = 0; l < N_LAYERS; ++l) {
        const unsigned short* Wlt = Wt + (size_t)l * HC * F_DIM;
        const unsigned short* Wrt = Wt + (size_t)(4 + l) * HC * F_DIM;
        const unsigned short* Wet = Wt + (size_t)(8 + l) * HC * F_DIM;
        proj_kernel<<<(N_NODES + 127) / 128, 256, 0, stream>>>(
            hin, a_input, N_NODES, Wlt, Wrt,
            bl, (size_t)l * HC, br, (size_t)l * HC,
            xl, xr, 8, flag);
        proj_kernel<<<(REL_EXT_ROWS + 127) / 128, 256, 0, stream>>>(
            rel_ext, 0, REL_EXT_ROWS, Wet, nullptr,
            nullptr, 0, nullptr, 0,
            re, nullptr, 4, flag);
        int final_layer = (l == N_LAYERS - 1);
        void* hout = final_layer ? d_out : (void*)hbuf;
        edge_kernel<<<N_NODES, 256, 0, stream>>>((const unsigned int*)xl, (const unsigned int*)xr,
                                                 (const unsigned int*)re, row_start, csr_pack,
                                                 att, (size_t)l * N_HEAD * F_DIM,
                                                 bias, (size_t)l * F_DIM,
                                                 hout, final_layer, flag);
        hin = hbuf;
        a_input = 0;
    }
}

// Round 7
// 494.729 us; speedup vs baseline: 2.0134x; 1.7576x over previous
//
#include <hip/hip_runtime.h>
#include <hip/hip_bf16.h>

#define N_NODES   20000
#define N_EDGES   100000
#define N_REL     1000
#define F_DIM     128
#define N_HEAD    4
#define HC        512      // N_HEAD * F_DIM
#define HC2       256      // HC/2 (bf16 pairs)
#define N_LAYERS  4
#define REL_EXT_ROWS 1008  // 1000 relations + 1 mean row
#define NEG_SLOPE 0.2f

typedef __attribute__((ext_vector_type(8))) short short8;
typedef __attribute__((ext_vector_type(4))) float floatx4;

__device__ __forceinline__ float loadIn(const void* p, size_t i, int f32) {
    if (f32) return ((const float*)p)[i];
    union { unsigned int u; float f; } c;
    c.u = ((unsigned int)((const unsigned short*)p)[i]) << 16;
    return c.f;
}

__device__ __forceinline__ unsigned short f2bf(float v) {
    __hip_bfloat16 b = __float2bfloat16(v);
    return *(unsigned short*)&b;
}

__device__ __forceinline__ void unpack2(unsigned int u, float& lo, float& hi) {
    union { unsigned int u; float f; } a, b;
    a.u = u << 16;
    b.u = u & 0xFFFF0000u;
    lo = a.f; hi = b.f;
}

// ---------------- dtype detection ----------------
__global__ void detect_kernel(const unsigned short* __restrict__ x, int* __restrict__ flag) {
    int t = threadIdx.x;  // 64
    int cnt = 0;
    for (int j = t; j < 256; j += 64) {
        int e = (x[j] >> 7) & 0xFF;
        if (e >= 143) cnt++;
    }
    for (int off = 32; off; off >>= 1) cnt += __shfl_xor(cnt, off);
    if (t == 0) flag[0] = (cnt >= 8) ? 1 : 0;
}

// ---------------- preprocessing ----------------

__global__ void hist_kernel(const int* __restrict__ dst, const int* __restrict__ rel,
                            int* __restrict__ deg, int* __restrict__ rcount) {
    int e = blockIdx.x * 256 + threadIdx.x;
    if (e < N_EDGES) {
        atomicAdd(&deg[dst[e]], 1);
        atomicAdd(&rcount[rel[e]], 1);
    }
}

__global__ void ea_mean_kernel(const int* __restrict__ rcount,
                               const void* __restrict__ relations,
                               float* __restrict__ ea_mean, const int* __restrict__ flag) {
    int f32 = flag[0];
    int b = blockIdx.x;
    int t = threadIdx.x;
    int col = t & 127;
    int rhalf = t >> 7;
    float acc = 0.f;
    for (int j = 0; j < 4; ++j) {
        int r = b * 8 + j * 2 + rhalf;
        acc += (float)rcount[r] * loadIn(relations, (size_t)r * F_DIM + col, f32);
    }
    __shared__ float part[256];
    part[t] = acc;
    __syncthreads();
    if (t < 128)
        atomicAdd(&ea_mean[col], (part[t] + part[t + 128]) * (1.f / (float)N_EDGES));
}

__global__ void relext_kernel(const void* __restrict__ relations,
                              const float* __restrict__ ea_mean,
                              unsigned short* __restrict__ rel_ext, const int* __restrict__ flag) {
    int idx = blockIdx.x * 256 + threadIdx.x;
    if (idx >= REL_EXT_ROWS * F_DIM) return;
    int f32 = flag[0];
    int r = idx >> 7;
    int c = idx & 127;
    float v;
    if (r < N_REL)       v = loadIn(relations, idx, f32);
    else if (r == N_REL) v = ea_mean[c];
    else                 v = 0.f;
    rel_ext[idx] = f2bf(v);
}

__global__ void scan_kernel(const int* __restrict__ deg,
                            int* __restrict__ row_start, int* __restrict__ cursor) {
    __shared__ int part[1024];
    int t = threadIdx.x;
    const int CH = (N_NODES + 1023) / 1024;  // 20
    int base = t * CH;
    int sum = 0;
    for (int j = 0; j < CH; ++j) {
        int idx = base + j;
        if (idx < N_NODES) sum += deg[idx];
    }
    part[t] = sum;
    __syncthreads();
    for (int off = 1; off < 1024; off <<= 1) {
        int u = (t >= off) ? part[t - off] : 0;
        __syncthreads();
        part[t] += u;
        __syncthreads();
    }
    int run = part[t] - sum;
    for (int j = 0; j < CH; ++j) {
        int idx = base + j;
        if (idx < N_NODES) {
            row_start[idx] = run;
            cursor[idx] = run;
            run += deg[idx];
        }
    }
    if (t == 1023) row_start[N_NODES] = part[1023];
}

__global__ void scatter_kernel(const int* __restrict__ src, const int* __restrict__ dst,
                               const int* __restrict__ rel, int* __restrict__ cursor,
                               int* __restrict__ csr_pack) {
    int e = blockIdx.x * 256 + threadIdx.x;
    if (e < N_EDGES) {
        int d = dst[e];
        int p = atomicAdd(&cursor[d], 1);
        csr_pack[p] = src[e] | (rel[e] << 16);
    }
}

__global__ void tail_kernel(const void* __restrict__ relations, void* __restrict__ out,
                            const int* __restrict__ flag) {
    int i = blockIdx.x * 256 + threadIdx.x;
    if (i >= N_REL * F_DIM) return;
    int f32 = flag[0];
    float v = loadIn(relations, i, f32);
    size_t o = (size_t)N_NODES * F_DIM + i;
    if (f32) ((float*)out)[o] = v;
    else     ((unsigned short*)out)[o] = f2bf(v);
}

// ---------------- weight transpose: W[l][128 k][512 n] -> Wt[mat][512 n][128 k] bf16 ----------------
__global__ void w_transpose_kernel(const void* __restrict__ Wl, const void* __restrict__ Wr,
                                   const void* __restrict__ We,
                                   unsigned short* __restrict__ Wt, const int* __restrict__ flag) {
    int f32 = flag[0];
    int k0 = blockIdx.x * 64;
    int n0 = blockIdx.y * 64;
    int mat = blockIdx.z;
    const void* src = (mat < 4) ? Wl : (mat < 8 ? Wr : We);
    size_t base = (size_t)(mat & 3) * F_DIM * HC;
    unsigned short* dst = Wt + (size_t)mat * HC * F_DIM;
    __shared__ float T[64][65];
    int t = threadIdx.x;
    int r = t >> 2, cq = t & 3;
    for (int j = 0; j < 16; ++j) {
        int n = cq * 16 + j;
        T[n][r] = loadIn(src, base + (size_t)(k0 + r) * HC + n0 + n, f32);
    }
    __syncthreads();
    for (int j = 0; j < 16; ++j) {
        int k = cq * 16 + j;
        dst[(size_t)(n0 + r) * F_DIM + k0 + k] = f2bf(T[r][k]);
    }
}

// ---------------- projection GEMM (latency-optimized grid) ----------------
// out[M x 512] = A[M x 128] @ W (+bias), one or two weight matrices.
// Block: 64 rows x (tpb n-tiles of 128 cols). grid (ceil(M/64), y) where block's
// tiles are [y*tpb, y*tpb+tpb); tile nt<4 -> Wt0/out0, else Wt1/out1.
// LDS: As[64][136] (full K) + BtRaw (Bt[128][72] per k-half, reused as Cs[64][136]
// for a coalesced short8 epilogue). 36 KB -> 4 blocks/CU.
// Wave = 32 rows x 64 cols (acc[2][4]). MFMA 16x16x32 bf16;
// C/D: col=lane&15, row=quad*4+reg.
__launch_bounds__(256, 4)
__global__ void proj_kernel(const void* __restrict__ A, int a_input, int M,
                            const unsigned short* __restrict__ Wt0,
                            const unsigned short* __restrict__ Wt1,
                            const void* __restrict__ bias0, size_t b0_off,
                            const void* __restrict__ bias1, size_t b1_off,
                            unsigned short* __restrict__ out0,
                            unsigned short* __restrict__ out1,
                            int tpb, const int* __restrict__ flag) {
    __shared__ __align__(16) short As[64][136];    // 17.4 KB
    __shared__ __align__(16) short BtRaw[128 * 72];// 18.4 KB; Cs view: stride 136, 64 rows
    int f32 = flag[0];
    int a_f32 = a_input ? f32 : 0;
    int m0 = blockIdx.x * 64;
    int t = threadIdx.x;

    // stage A once: 64 rows x 128 K (short8 chunks)
    for (int j = 0; j < 4; ++j) {
        int c = t + j * 256;
        int row = c >> 4;           // 0..63
        int colc = (c & 15) * 8;    // 0..120
        int gm = m0 + row;
        short8 v = (short8){0, 0, 0, 0, 0, 0, 0, 0};
        if (gm < M) {
            size_t idx = (size_t)gm * F_DIM + colc;
            if (a_f32) {
                const float* Af = (const float*)A;
                for (int q = 0; q < 8; ++q) v[q] = (short)f2bf(Af[idx + q]);
            } else {
                v = *(const short8*)((const unsigned short*)A + idx);
            }
        }
        *(short8*)&As[row][colc] = v;
    }

    int wave = t >> 6, lane = t & 63;
    int wm = (wave >> 1) * 32, wn = (wave & 1) * 64;
    int r16 = lane & 15, quad = lane >> 4;

    for (int it = 0; it < tpb; ++it) {
        int nt = blockIdx.y * tpb + it;
        const unsigned short* Wt = (nt < 4) ? Wt0 : Wt1;
        int n0 = (nt & 3) * 128;

        floatx4 acc[2][4];
        for (int mi = 0; mi < 2; ++mi)
            for (int ni = 0; ni < 4; ++ni)
                acc[mi][ni] = (floatx4){0.f, 0.f, 0.f, 0.f};

        for (int half = 0; half < 2; ++half) {
            __syncthreads();   // As visible (first use); prev Bt/Cs reads retired
            for (int j = 0; j < 4; ++j) {
                int c = t + j * 256;        // 0..1023
                int nl = c >> 3;            // 0..127
                int kc = (c & 7) * 8;       // 0..56
                *(short8*)&BtRaw[nl * 72 + kc] =
                    *(const short8*)(Wt + (size_t)(n0 + nl) * F_DIM + half * 64 + kc);
            }
            __syncthreads();

            for (int kk = 0; kk < 2; ++kk) {
                short8 a[2], b[4];
                for (int mi = 0; mi < 2; ++mi)
                    a[mi] = *(const short8*)&As[wm + mi * 16 + r16][half * 64 + kk * 32 + quad * 8];
                for (int ni = 0; ni < 4; ++ni)
                    b[ni] = *(const short8*)&BtRaw[(wn + ni * 16 + r16) * 72 + kk * 32 + quad * 8];
                for (int mi = 0; mi < 2; ++mi)
                    for (int ni = 0; ni < 4; ++ni)
                        acc[mi][ni] = __builtin_amdgcn_mfma_f32_16x16x32_bf16(a[mi], b[ni], acc[mi][ni], 0, 0, 0);
            }
        }

        // epilogue: acc -> Cs (bf16, bias added) -> coalesced short8 stores
        const void* bias = (nt < 4) ? bias0 : bias1;
        size_t boff = (nt < 4) ? b0_off : b1_off;
        unsigned short* out = (nt < 4) ? out0 : out1;
        __syncthreads();   // all Bt reads done before overwrite as Cs
        for (int mi = 0; mi < 2; ++mi) {
            for (int ni = 0; ni < 4; ++ni) {
                int col = wn + ni * 16 + r16;
                float bv = bias ? loadIn(bias, boff + n0 + col, f32) : 0.f;
                for (int r = 0; r < 4; ++r) {
                    int rowl = wm + mi * 16 + quad * 4 + r;
                    BtRaw[rowl * 136 + col] = (short)f2bf(acc[mi][ni][r] + bv);
                }
            }
        }
        __syncthreads();
        for (int j = 0; j < 4; ++j) {
            int c = t + j * 256;
            int rowl = c >> 4;          // 0..63
            int colc = (c & 15) * 8;    // 0..120
            int gm = m0 + rowl;
            if (gm < M)
                *(short8*)(out + (size_t)gm * HC + n0 + colc) =
                    *(const short8*)&BtRaw[rowl * 136 + colc];
        }
    }
}

// ---------------- edge scoring + segment softmax + aggregation + head mean ----------------
__launch_bounds__(256)
__global__ void edge_kernel(const unsigned int* __restrict__ xl2,
                            const unsigned int* __restrict__ xr2,
                            const unsigned int* __restrict__ re2,
                            const int* __restrict__ row_start,
                            const int* __restrict__ csr_pack,
                            const void* __restrict__ att, size_t att_off,
                            const void* __restrict__ bias, size_t bias_off,
                            void* __restrict__ hout, int final_layer,
                            const int* __restrict__ flag) {
    int f32 = flag[0];
    int i = blockIdx.x;
    int h = threadIdx.x >> 6;
    int lane = threadIdx.x & 63;
    int pidx = h * 64 + lane;

    float xr0, xr1; unpack2(xr2[(size_t)i * HC2 + pidx], xr0, xr1);
    float a0 = loadIn(att, att_off + h * F_DIM + 2 * lane, f32);
    float a1 = loadIn(att, att_off + h * F_DIM + 2 * lane + 1, f32);
    float er0, er1; unpack2(re2[(size_t)N_REL * HC2 + pidx], er0, er1);

    // self-loop first
    float xs0, xs1; unpack2(xl2[(size_t)i * HC2 + pidx], xs0, xs1);
    float t0 = xs0 + xr0 + er0;
    float t1 = xs1 + xr1 + er1;
    t0 = (t0 > 0.f) ? t0 : NEG_SLOPE * t0;
    t1 = (t1 > 0.f) ? t1 : NEG_SLOPE * t1;
    float m = t0 * a0 + t1 * a1;
    for (int off = 32; off; off >>= 1) m += __shfl_xor(m, off);
    float s = 1.f, acc0 = xs0, acc1 = xs1;

    int e0 = row_start[i], e1 = row_start[i + 1];
    if (e0 < 0) e0 = 0;
    if (e1 > N_EDGES) e1 = N_EDGES;
    if (e1 < e0) e1 = e0;

    unsigned int xlv = 0, rev = 0;
    if (e0 < e1) {
        int pk = csr_pack[e0];
        int src = pk & 0xFFFF;  if (src >= N_NODES) src = 0;
        int rr  = (pk >> 16) & 0x3FF; if (rr > N_REL) rr = N_REL;
        xlv = xl2[(size_t)src * HC2 + pidx];
        rev = re2[(size_t)rr * HC2 + pidx];
    }
    for (int e = e0; e < e1; ++e) {
        unsigned int xlvn = 0, revn = 0;
        if (e + 1 < e1) {
            int pkn = csr_pack[e + 1];
            int sn = pkn & 0xFFFF;  if (sn >= N_NODES) sn = 0;
            int rn = (pkn >> 16) & 0x3FF; if (rn > N_REL) rn = N_REL;
            xlvn = xl2[(size_t)sn * HC2 + pidx];
            revn = re2[(size_t)rn * HC2 + pidx];
        }
        float xl0, xl1; unpack2(xlv, xl0, xl1);
        float ee0, ee1; unpack2(rev, ee0, ee1);
        float u0 = xl0 + xr0 + ee0;
        float u1 = xl1 + xr1 + ee1;
        u0 = (u0 > 0.f) ? u0 : NEG_SLOPE * u0;
        u1 = (u1 > 0.f) ? u1 : NEG_SLOPE * u1;
        float part = u0 * a0 + u1 * a1;
        for (int off = 32; off; off >>= 1) part += __shfl_xor(part, off);
        float mn = fmaxf(m, part);
        float sc = __expf(m - mn);
        float p  = __expf(part - mn);
        s = s * sc + p;
        acc0 = acc0 * sc + p * xl0;
        acc1 = acc1 * sc + p * xl1;
        m = mn;
        xlv = xlvn; rev = revn;
    }

    float inv = 1.f / s;
    __shared__ float lsum[N_HEAD][F_DIM];
    lsum[h][2 * lane]     = acc0 * inv;
    lsum[h][2 * lane + 1] = acc1 * inv;
    __syncthreads();
    if (threadIdx.x < F_DIM) {
        int c = threadIdx.x;
        float v = (lsum[0][c] + lsum[1][c] + lsum[2][c] + lsum[3][c]) * 0.25f
                + loadIn(bias, bias_off + c, f32);
        size_t o = (size_t)i * F_DIM + c;
        if (final_layer && f32) ((float*)hout)[o] = v;
        else                    ((unsigned short*)hout)[o] = f2bf(v);
    }
}

// ---------------- launch ----------------

extern "C" void kernel_launch(void* const* d_in, const int* in_sizes, int n_in,
                              void* d_out, int out_size, void* d_ws, size_t ws_size,
                              hipStream_t stream) {
    const void* x          = d_in[0];
    const int*  edge_index = (const int*)d_in[1];
    const void* relations  = d_in[2];
    const int*  rel_index  = (const int*)d_in[3];
    const void* Wl         = d_in[4];
    const void* bl         = d_in[5];
    const void* Wr         = d_in[6];
    const void* br         = d_in[7];
    const void* We         = d_in[8];
    const void* att        = d_in[9];
    const void* bias       = d_in[10];

    char* ws = (char*)d_ws;
    size_t off = 0;
    auto alloc = [&](size_t bytes) -> void* {
        void* p = ws + off;
        off = (off + bytes + 255) & ~(size_t)255;
        return p;
    };
    int*            flag     = (int*)alloc(4);
    int*            deg      = (int*)alloc(N_NODES * 4);
    int*            row_start= (int*)alloc((N_NODES + 1) * 4);
    int*            cursor   = (int*)alloc(N_NODES * 4);
    int*            rcount   = (int*)alloc(N_REL * 4);
    float*          ea_mean  = (float*)alloc(F_DIM * 4);
    int*            csr_pack = (int*)alloc(N_EDGES * 4);
    unsigned short* rel_ext  = (unsigned short*)alloc((size_t)REL_EXT_ROWS * F_DIM * 2);
    unsigned short* Wt       = (unsigned short*)alloc((size_t)12 * HC * F_DIM * 2);  // 1.57 MB
    unsigned short* re       = (unsigned short*)alloc((size_t)REL_EXT_ROWS * HC * 2);
    unsigned short* hbuf     = (unsigned short*)alloc((size_t)N_NODES * F_DIM * 2);
    unsigned short* xl       = (unsigned short*)alloc((size_t)N_NODES * HC * 2);
    unsigned short* xr       = (unsigned short*)alloc((size_t)N_NODES * HC * 2);
    // total ~49 MB

    const int* esrc = edge_index;
    const int* edst = edge_index + N_EDGES;

    detect_kernel<<<1, 64, 0, stream>>>((const unsigned short*)x, flag);
    hipMemsetAsync(rcount, 0, N_REL * 4, stream);
    hipMemsetAsync(deg, 0, N_NODES * 4, stream);
    hipMemsetAsync(ea_mean, 0, F_DIM * 4, stream);
    hist_kernel<<<(N_EDGES + 255) / 256, 256, 0, stream>>>(edst, rel_index, deg, rcount);
    ea_mean_kernel<<<N_REL / 8, 256, 0, stream>>>(rcount, relations, ea_mean, flag);
    relext_kernel<<<(REL_EXT_ROWS * F_DIM + 255) / 256, 256, 0, stream>>>(relations, ea_mean, rel_ext, flag);
    scan_kernel<<<1, 1024, 0, stream>>>(deg, row_start, cursor);
    scatter_kernel<<<(N_EDGES + 255) / 256, 256, 0, stream>>>(esrc, edst, rel_index, cursor, csr_pack);
    w_transpose_kernel<<<dim3(2, 8, 12), 256, 0, stream>>>(Wl, Wr, We, Wt, flag);
    tail_kernel<<<(N_REL * F_DIM + 255) / 256, 256, 0, stream>>>(relations, d_out, flag);

    const void* hin = x;
    int a_input = 1;
    for (int l = 0; l < N_LAYERS; ++l) {
        const unsigned short* Wlt = Wt + (size_t)l * HC * F_DIM;
        const unsigned short* Wrt = Wt + (size_t)(4 + l) * HC * F_DIM;
        const unsigned short* Wet = Wt + (size_t)(8 + l) * HC * F_DIM;
        // node proj: 313 m-tiles x 4 n-groups (2 tiles each: y<2 -> Wl, y>=2 -> Wr)
        proj_kernel<<<dim3((N_NODES + 63) / 64, 4), 256, 0, stream>>>(
            hin, a_input, N_NODES, Wlt, Wrt,
            bl, (size_t)l * HC, br, (size_t)l * HC,
            xl, xr, 2, flag);
        // rel proj: 16 m-tiles x 4 n-groups (1 tile each)
        proj_kernel<<<dim3((REL_EXT_ROWS + 63) / 64, 4), 256, 0, stream>>>(
            rel_ext, 0, REL_EXT_ROWS, Wet, nullptr,
            nullptr, 0, nullptr, 0,
            re, nullptr, 1, flag);
        int final_layer = (l == N_LAYERS - 1);
        void* hout = final_layer ? d_out : (void*)hbuf;
        edge_kernel<<<N_NODES, 256, 0, stream>>>((const unsigned int*)xl, (const unsigned int*)xr,
                                                 (const unsigned int*)re, row_start, csr_pack,
                                                 att, (size_t)l * N_HEAD * F_DIM,
                                                 bias, (size_t)l * F_DIM,
                                                 hout, final_layer, flag);
        hin = hbuf;
        a_input = 0;
    }
}